// Round 12
// baseline (15.920 us; speedup 1.0000x reference)
//
#include <hip/hip_runtime.h>

#define NATOMS 25000
#define NSP 64
#define NRANGE 16
#define RSIZE ((NATOMS + NRANGE - 1) / NRANGE)   // 1563 atoms per range
#define NWAVE 4
#define WSUB ((RSIZE + NWAVE - 1) / NWAVE)       // 391 atoms per wave
#define WIT ((WSUB + 63) / 64)                   // 7 scan iters per wave
#define LCAP (WIT * 64)                          // 448

typedef short bf16x8 __attribute__((ext_vector_type(8)));   // 8 bf16 = 4 VGPRs
typedef float f32x4  __attribute__((ext_vector_type(4)));
typedef unsigned short u16;

// f32 -> bf16 round-to-nearest-even
__device__ __forceinline__ u16 f2bf(float f) {
  unsigned u = __float_as_uint(f);
  u += 0x7fffu + ((u >> 16) & 1u);
  return (u16)(u >> 16);
}

// Single kernel, 1024 blocks = 64 species x 16 ranges, 256 thr.
// VGPR discipline: peak ~110 <= 128 (4 waves/SIMD); LDS 35.6KB (4 blocks/CU).
// Key change vs R11: BOTH W rounds issued before the scan (round B parked in
// the pf[8] registers), and tile-0 feat + bias issued BEFORE the barrier, so
// no memory round-trip is serially exposed between scan and first MFMA.
__global__ __launch_bounds__(256)
void zcl_kernel(const float* __restrict__ feat,
                const int*   __restrict__ sp,
                const float* __restrict__ weight,
                const float* __restrict__ bias,
                float*       __restrict__ out)
{
  // W[o][i] bf16, rows of 128; 16B chunks XOR-swizzled by (row&7) so B-frag
  // ds_read_b128 (lanes differ in row, fixed k-chunk) spreads all 32 banks.
  __shared__ u16 Ws[128 * 128];        // 32 KiB
  __shared__ u16 wlist[NWAVE][LCAP];   // 3.5 KiB wave-private lists

  const int tid = threadIdx.x, bid = blockIdx.x;
  // XCD pin: species s -> XCD s%8; W f32 set/XCD = 8 sp * 64KB = 512KB L2-hot.
  const int s = (bid & 7) + 8 * ((bid >> 3) & 7);
  const int r = bid >> 6;
  const int lo = r * RSIZE;
  const int hi = (lo + RSIZE < NATOMS) ? (lo + RSIZE) : NATOMS;

  const int wv = tid >> 6, lane = tid & 63;
  const int l16 = lane & 15, kq = lane >> 4;
  const int wlo = lo + wv * WSUB;
  const int whi = (wlo + WSUB < hi) ? (wlo + WSUB) : hi;

  // ---- prologue: issue EVERYTHING independent up front ----
  // 1) sp (oldest in vmcnt FIFO -> scan's counted wait leaves the rest in flight)
  int spv[WIT];
  #pragma unroll
  for (int i = 0; i < WIT; ++i) {
    int a = wlo + i * 64 + lane;
    spv[i] = (a < hi) && (a < whi) ? sp[a] : -1;
  }
  // 2) bias (consumed only at stores; 8 dwords, L2-hot)
  float bvb[8];
  #pragma unroll
  for (int nf = 0; nf < 8; ++nf) bvb[nf] = bias[s * 128 + l16 + 16 * nf];
  // 3) W round A -> wA (32 VGPR), round B -> pf (32 VGPR, time-shared)
  const float4* wg = (const float4*)(weight + (size_t)s * (128 * 128));
  float4 wA[8], pf[8];
  #pragma unroll
  for (int q = 0; q < 4; ++q) {
    int m = q * 256 + tid;               // chunk: row=m>>4, 8-elem group c=m&15
    int row = m >> 4, c = m & 15;
    wA[2 * q]     = wg[row * 32 + c * 2];
    wA[2 * q + 1] = wg[row * 32 + c * 2 + 1];
  }
  #pragma unroll
  for (int q = 0; q < 4; ++q) {
    int m = 1024 + q * 256 + tid;
    int row = m >> 4, c = m & 15;
    pf[2 * q]     = wg[row * 32 + c * 2];
    pf[2 * q + 1] = wg[row * 32 + c * 2 + 1];
  }

  // ---- scan (waits only on sp; all W loads still in flight) ----
  int wcnt = 0;
  #pragma unroll
  for (int i = 0; i < WIT; ++i) {
    bool m = (spv[i] == s);
    unsigned long long mk = __ballot(m);
    if (m) wlist[wv][wcnt + __popcll(mk & ((1ull << lane) - 1ull))] =
             (u16)(wlo + i * 64 + lane);
    wcnt += (int)__popcll(mk);
  }
  const int nt = (wcnt + 15) >> 4;

  // ---- convert W round A, then round B (from pf) ----
  #pragma unroll
  for (int q = 0; q < 4; ++q) {
    int m = q * 256 + tid;
    int row = m >> 4, c = m & 15;
    union { u16 h[8]; bf16x8 v; } uu;
    uu.h[0] = f2bf(wA[2 * q].x);     uu.h[1] = f2bf(wA[2 * q].y);
    uu.h[2] = f2bf(wA[2 * q].z);     uu.h[3] = f2bf(wA[2 * q].w);
    uu.h[4] = f2bf(wA[2 * q + 1].x); uu.h[5] = f2bf(wA[2 * q + 1].y);
    uu.h[6] = f2bf(wA[2 * q + 1].z); uu.h[7] = f2bf(wA[2 * q + 1].w);
    *(bf16x8*)&Ws[row * 128 + ((c ^ (row & 7)) << 3)] = uu.v;
  }
  #pragma unroll
  for (int q = 0; q < 4; ++q) {
    int m = 1024 + q * 256 + tid;
    int row = m >> 4, c = m & 15;
    union { u16 h[8]; bf16x8 v; } uu;
    uu.h[0] = f2bf(pf[2 * q].x);     uu.h[1] = f2bf(pf[2 * q].y);
    uu.h[2] = f2bf(pf[2 * q].z);     uu.h[3] = f2bf(pf[2 * q].w);
    uu.h[4] = f2bf(pf[2 * q + 1].x); uu.h[5] = f2bf(pf[2 * q + 1].y);
    uu.h[6] = f2bf(pf[2 * q + 1].z); uu.h[7] = f2bf(pf[2 * q + 1].w);
    *(bf16x8*)&Ws[row * 128 + ((c ^ (row & 7)) << 3)] = uu.v;
  }

  // ---- tile-0 feat prefetch into pf BEFORE the barrier (RT hides under it) ----
  if (nt > 0) {
    int atomA = wlist[wv][l16 < wcnt ? l16 : 0];   // wave-local list: no barrier needed
    const float4* xg = (const float4*)(feat + (size_t)atomA * 128);
    #pragma unroll
    for (int ks = 0; ks < 4; ++ks) {
      pf[2 * ks]     = xg[ks * 8 + kq * 2];
      pf[2 * ks + 1] = xg[ks * 8 + kq * 2 + 1];
    }
  }

  __syncthreads();   // Ws visible to all waves
  if (nt == 0) return;

  // ---- wave-independent tile loop (16 atoms x 128 outs x K=128) ----
  for (int t = 0; t < nt; ++t) {
    bf16x8 av[4];
    #pragma unroll
    for (int ks = 0; ks < 4; ++ks) {
      union { u16 h[8]; bf16x8 v; } uu;
      uu.h[0] = f2bf(pf[2 * ks].x);     uu.h[1] = f2bf(pf[2 * ks].y);
      uu.h[2] = f2bf(pf[2 * ks].z);     uu.h[3] = f2bf(pf[2 * ks].w);
      uu.h[4] = f2bf(pf[2 * ks + 1].x); uu.h[5] = f2bf(pf[2 * ks + 1].y);
      uu.h[6] = f2bf(pf[2 * ks + 1].z); uu.h[7] = f2bf(pf[2 * ks + 1].w);
      av[ks] = uu.v;
    }

    if (t + 1 < nt) {   // prefetch next tile (overlaps MFMA + stores)
      int li = (t + 1) * 16 + l16;
      int atomA = wlist[wv][li < wcnt ? li : 0];
      const float4* xg = (const float4*)(feat + (size_t)atomA * 128);
      #pragma unroll
      for (int ks = 0; ks < 4; ++ks) {
        pf[2 * ks]     = xg[ks * 8 + kq * 2];
        pf[2 * ks + 1] = xg[ks * 8 + kq * 2 + 1];
      }
    }

    f32x4 acc[8];
    #pragma unroll
    for (int nf = 0; nf < 8; ++nf) acc[nf] = (f32x4){0.f, 0.f, 0.f, 0.f};
    #pragma unroll
    for (int ks = 0; ks < 4; ++ks) {
      int chunk = ((ks * 4 + kq) ^ (l16 & 7)) << 3;   // row&7 == l16&7 for all nf
      #pragma unroll
      for (int nf = 0; nf < 8; ++nf) {
        bf16x8 b = *(const bf16x8*)&Ws[(l16 + 16 * nf) * 128 + chunk];
        acc[nf] = __builtin_amdgcn_mfma_f32_16x16x32_bf16(av[ks], b, acc[nf], 0, 0, 0);
      }
    }

    // store: D row = kq*4+q -> atom; col = l16 -> out channel l16+16*nf
    #pragma unroll
    for (int q = 0; q < 4; ++q) {
      int li2 = t * 16 + kq * 4 + q;
      if (li2 < wcnt) {
        int atom = wlist[wv][li2];
        float* op = out + (size_t)atom * 128 + l16;
        #pragma unroll
        for (int nf = 0; nf < 8; ++nf) op[16 * nf] = acc[nf][q] + bvb[nf];
      }
    }
  }
}

extern "C" void kernel_launch(void* const* d_in, const int* in_sizes, int n_in,
                              void* d_out, int out_size, void* d_ws, size_t ws_size,
                              hipStream_t stream) {
  const float* feat   = (const float*)d_in[0];
  const int*   sp     = (const int*)d_in[1];
  const float* weight = (const float*)d_in[2];
  const float* bias   = (const float*)d_in[3];
  float*       out    = (float*)d_out;
  zcl_kernel<<<NSP * NRANGE, 256, 0, stream>>>(feat, sp, weight, bias, out);
}